// Round 3
// baseline (286.770 us; speedup 1.0000x reference)
//
#include <hip/hip_runtime.h>

#define NB 4
#define SEQ 4096
#define DIMK 1024
#define DKV 128
#define SCALE 0.08838834764831845f   // 1/sqrt(128)

typedef float  f32x4 __attribute__((ext_vector_type(4)));
typedef _Float16 f16x8 __attribute__((ext_vector_type(8)));

// ---------------- kernel 0: transpose W -> f16 WT[3][128][1024] ----------------
__global__ void prep_wt(const float* __restrict__ Wq, const float* __restrict__ Wk,
                        const float* __restrict__ Wv, _Float16* __restrict__ WT) {
    int tid = blockIdx.x * 256 + threadIdx.x;        // 3*1024*128 = 393216 threads
    int n  = tid & 127;
    int k  = (tid >> 7) & 1023;
    int w3 = tid >> 17;
    const float* W = (w3 == 0) ? Wq : (w3 == 1) ? Wk : Wv;
    WT[((size_t)w3 * 128 + n) * 1024 + k] = (_Float16)W[(size_t)k * 128 + n];
}

// ---------------- kernel 1: QKV projection, w3-split (unchanged, verified) ----------------
__global__ __launch_bounds__(256) void qkv_proj(
    const float* __restrict__ X,
    const float* __restrict__ bq, const float* __restrict__ bk, const float* __restrict__ bv,
    const _Float16* __restrict__ WT,
    _Float16* __restrict__ Qh, _Float16* __restrict__ Kh, _Float16* __restrict__ VTh) {

    __shared__ __attribute__((aligned(16))) _Float16 WTs[128 * 40];
    const int t = threadIdx.x;
    const int w = t >> 6, l = t & 63;
    const int lrow = l & 15, lg = l >> 4;
    const int w3   = blockIdx.x % 3;
    const int tile = blockIdx.x / 3;
    const int r0 = tile * 64;

    f32x4 acc[8] = {};
    const float* xrow = X + (size_t)(r0 + w * 16 + lrow) * DIMK;
    const _Float16* Wbase = WT + (size_t)w3 * 128 * 1024;

    for (int k0 = 0; k0 < DIMK; k0 += 32) {
        __syncthreads();
        #pragma unroll
        for (int i = 0; i < 2; ++i) {
            int c = t + 256 * i;
            int row = c >> 2, part = c & 3;
            *(int4*)((char*)WTs + row * 80 + part * 16) =
                *(const int4*)(Wbase + (size_t)row * 1024 + k0 + part * 8);
        }
        __syncthreads();
        f16x8 a;
        const float* xp = xrow + k0 + lg * 8;
        float4 x0 = *(const float4*)(xp);
        float4 x1 = *(const float4*)(xp + 4);
        a[0] = (_Float16)x0.x; a[1] = (_Float16)x0.y; a[2] = (_Float16)x0.z; a[3] = (_Float16)x0.w;
        a[4] = (_Float16)x1.x; a[5] = (_Float16)x1.y; a[6] = (_Float16)x1.z; a[7] = (_Float16)x1.w;

        #pragma unroll
        for (int n = 0; n < 8; ++n) {
            f16x8 bf = *(const f16x8*)((const char*)WTs + (n * 16 + lrow) * 80 + lg * 16);
            acc[n] = __builtin_amdgcn_mfma_f32_16x16x32_f16(a, bf, acc[n], 0, 0, 0);
        }
    }
    const float* bias = (w3 == 0) ? bq : (w3 == 1) ? bk : bv;
    #pragma unroll
    for (int n = 0; n < 8; ++n) {
        int col = n * 16 + lrow;
        float bv_ = bias[col];
        #pragma unroll
        for (int j = 0; j < 4; ++j) {
            int grow = r0 + w * 16 + lg * 4 + j;
            float val = acc[n][j] + bv_;
            if (w3 == 0) {
                Qh[(size_t)grow * DKV + col] = (_Float16)(val * SCALE);
            } else if (w3 == 1) {
                Kh[(size_t)grow * DKV + col] = (_Float16)val;
            } else {
                int b = grow >> 12, sp = grow & 4095;
                VTh[((size_t)b * DKV + col) * SEQ + sp] = (_Float16)val;
            }
        }
    }
}

// ---------------- kernel 2: flash attention, in-block 4-way KV-split ----------------
// grid 256 (XCD-swizzled), block 1024 thr = 16 waves = 4 groups x 4 waves.
// Group g handles keys [g*1024, (g+1)*1024) for the block's 64 q-rows; LDS tree-merge.
// LDS: Ks 4x16KB + VTs 4x16KB + Ps 16x2KB = 163840 B (exactly 160 KiB).
__global__ __launch_bounds__(1024, 4) void attn_kernel(
    const _Float16* __restrict__ Qh, const _Float16* __restrict__ Kh,
    const _Float16* __restrict__ VTh, float* __restrict__ out) {

    __shared__ __attribute__((aligned(16))) _Float16 Ks[4][64 * 128];
    __shared__ __attribute__((aligned(16))) _Float16 VTs[4][128 * 64];
    __shared__ __attribute__((aligned(16))) _Float16 Ps[16][16 * 64];

    const int t = threadIdx.x;
    const int w = t >> 6, l = t & 63;
    const int lrow = l & 15, lg = l >> 4;
    const int g  = t >> 8;            // kv group 0..3 (256 contiguous threads)
    const int wq = w & 3;             // q-sub-block within the 64 q-rows
    const int lt = t & 255;           // thread within group (for staging)

    // XCD-chunked swizzle: XCD x gets contiguous works [x*32, x*32+32)
    const int work = (blockIdx.x & 7) * 32 + (blockIdx.x >> 3);
    const int b  = work >> 6;
    const int qt = work & 63;
    const int qrow = b * SEQ + qt * 64 + wq * 16 + lrow;

    f16x8 qfrag[4];
    #pragma unroll
    for (int ds = 0; ds < 4; ++ds)
        qfrag[ds] = *(const f16x8*)(Qh + (size_t)qrow * DKV + ds * 32 + lg * 8);

    f32x4 o[8] = {};
    float mrun[4] = {-INFINITY, -INFINITY, -INFINITY, -INFINITY};
    float lrun[4] = {0.f, 0.f, 0.f, 0.f};

    char* KsG = (char*)&Ks[g][0];
    char* VsG = (char*)&VTs[g][0];
    char* PsW = (char*)&Ps[w][0];

    for (int kt = 0; kt < 16; ++kt) {
        const int k0 = g * 1024 + kt * 64;
        __syncthreads();
        // stage K tile 64x128 f16 (group-private), XOR-swizzled
        #pragma unroll
        for (int i = 0; i < 4; ++i) {
            int c = lt + 256 * i; int row = c >> 4, part = c & 15;
            *(int4*)(KsG + row * 256 + ((part * 16) ^ ((row & 7) << 4))) =
                *(const int4*)(Kh + (size_t)(b * SEQ + k0 + row) * DKV + part * 8);
        }
        // stage V^T tile 128x64 f16 (group-private), swizzled
        #pragma unroll
        for (int i = 0; i < 4; ++i) {
            int c = lt + 256 * i; int dv = c >> 3, part = c & 7;
            *(int4*)(VsG + dv * 128 + ((part * 16) ^ ((dv & 7) << 4))) =
                *(const int4*)(VTh + (size_t)(b * DKV + dv) * SEQ + k0 + part * 8);
        }
        __syncthreads();

        // S = Q K^T (scale folded into Q)
        f32x4 sacc[4] = {};
        #pragma unroll
        for (int n = 0; n < 4; ++n) {
            int rn = n * 16 + lrow;
            #pragma unroll
            for (int ds = 0; ds < 4; ++ds) {
                f16x8 kf = *(const f16x8*)(KsG + rn * 256 +
                                           ((ds * 64 + lg * 16) ^ ((rn & 7) << 4)));
                sacc[n] = __builtin_amdgcn_mfma_f32_16x16x32_f16(qfrag[ds], kf, sacc[n], 0, 0, 0);
            }
        }

        // online softmax with defer-max (T13, THR=8)
        float mt[4], ls[4];
        #pragma unroll
        for (int j = 0; j < 4; ++j)
            mt[j] = fmaxf(fmaxf(sacc[0][j], sacc[1][j]), fmaxf(sacc[2][j], sacc[3][j]));
        #pragma unroll
        for (int off = 1; off <= 8; off <<= 1)
            #pragma unroll
            for (int j = 0; j < 4; ++j)
                mt[j] = fmaxf(mt[j], __shfl_xor(mt[j], off));

        int need = (mt[0] > mrun[0] + 8.f) | (mt[1] > mrun[1] + 8.f) |
                   (mt[2] > mrun[2] + 8.f) | (mt[3] > mrun[3] + 8.f);
        if (__any(need)) {
            #pragma unroll
            for (int j = 0; j < 4; ++j) {
                float mnew = fmaxf(mrun[j], mt[j]);
                float corr = __expf(mrun[j] - mnew);
                mrun[j] = mnew;
                ls[j] = 0.f;
                #pragma unroll
                for (int n = 0; n < 4; ++n) {
                    sacc[n][j] = __expf(sacc[n][j] - mnew);
                    ls[j] += sacc[n][j];
                }
                #pragma unroll
                for (int n = 0; n < 8; ++n) o[n][j] *= corr;
                lrun[j] *= corr;
            }
        } else {
            #pragma unroll
            for (int j = 0; j < 4; ++j) {
                ls[j] = 0.f;
                #pragma unroll
                for (int n = 0; n < 4; ++n) {
                    sacc[n][j] = __expf(sacc[n][j] - mrun[j]);
                    ls[j] += sacc[n][j];
                }
            }
        }
        #pragma unroll
        for (int off = 1; off <= 8; off <<= 1)
            #pragma unroll
            for (int j = 0; j < 4; ++j)
                ls[j] += __shfl_xor(ls[j], off);
        #pragma unroll
        for (int j = 0; j < 4; ++j) lrun[j] += ls[j];

        // P -> wave-private LDS (128B rows, swizzled); no block barrier needed
        #pragma unroll
        for (int n = 0; n < 4; ++n)
            #pragma unroll
            for (int j = 0; j < 4; ++j) {
                int r = lg * 4 + j;
                *((_Float16*)(PsW + r * 128 +
                              (((n * 16 + lrow) * 2) ^ ((r & 7) << 4)))) = (_Float16)sacc[n][j];
            }
        asm volatile("s_waitcnt lgkmcnt(0)" ::: "memory");

        // O += P V
        #pragma unroll
        for (int h = 0; h < 2; ++h) {
            f16x8 pf = *(const f16x8*)(PsW + lrow * 128 +
                                       ((h * 64 + lg * 16) ^ ((lrow & 7) << 4)));
            #pragma unroll
            for (int n = 0; n < 8; ++n) {
                int rv = n * 16 + lrow;
                f16x8 vf = *(const f16x8*)(VsG + rv * 128 +
                                           ((h * 64 + lg * 16) ^ ((rv & 7) << 4)));
                o[n] = __builtin_amdgcn_mfma_f32_16x16x32_f16(pf, vf, o[n], 0, 0, 0);
            }
        }
    }

    // -------- tree-merge of 4 group partials via LDS (reuses Ks/VTs space) --------
    float* obuf  = (float*)&Ks[0][0];    // 2 buffers x 64x128 f32 = 64 KB
    float* mlbuf = (float*)&VTs[0][0];   // 2 x 64 x {m,l}

    __syncthreads();
    // round A: groups 1,3 publish; groups 0,2 merge
    if (g == 1 || g == 3) {
        int sb = (g == 3);
        #pragma unroll
        for (int n = 0; n < 8; ++n)
            #pragma unroll
            for (int j = 0; j < 4; ++j)
                obuf[sb * 8192 + (wq * 16 + lg * 4 + j) * 128 + n * 16 + lrow] = o[n][j];
        if (lrow == 0)
            #pragma unroll
            for (int j = 0; j < 4; ++j) {
                int r = wq * 16 + lg * 4 + j;
                mlbuf[sb * 128 + r * 2 + 0] = mrun[j];
                mlbuf[sb * 128 + r * 2 + 1] = lrun[j];
            }
    }
    __syncthreads();
    if (g == 0 || g == 2) {
        int sb = (g == 2);
        #pragma unroll
        for (int j = 0; j < 4; ++j) {
            int r = wq * 16 + lg * 4 + j;
            float mb = mlbuf[sb * 128 + r * 2 + 0];
            float lb = mlbuf[sb * 128 + r * 2 + 1];
            float mn = fmaxf(mrun[j], mb);
            float ca = __expf(mrun[j] - mn);
            float cb = __expf(mb - mn);
            mrun[j] = mn;
            lrun[j] = lrun[j] * ca + lb * cb;
            #pragma unroll
            for (int n = 0; n < 8; ++n)
                o[n][j] = o[n][j] * ca + obuf[sb * 8192 + r * 128 + n * 16 + lrow] * cb;
        }
    }
    __syncthreads();
    // round B: group 2 publishes merged; group 0 merges and writes out
    if (g == 2) {
        #pragma unroll
        for (int n = 0; n < 8; ++n)
            #pragma unroll
            for (int j = 0; j < 4; ++j)
                obuf[(wq * 16 + lg * 4 + j) * 128 + n * 16 + lrow] = o[n][j];
        if (lrow == 0)
            #pragma unroll
            for (int j = 0; j < 4; ++j) {
                int r = wq * 16 + lg * 4 + j;
                mlbuf[r * 2 + 0] = mrun[j];
                mlbuf[r * 2 + 1] = lrun[j];
            }
    }
    __syncthreads();
    if (g == 0) {
        #pragma unroll
        for (int j = 0; j < 4; ++j) {
            int r = wq * 16 + lg * 4 + j;
            float mb = mlbuf[r * 2 + 0];
            float lb = mlbuf[r * 2 + 1];
            float mn = fmaxf(mrun[j], mb);
            float ca = __expf(mrun[j] - mn);
            float cb = __expf(mb - mn);
            float lfin = lrun[j] * ca + lb * cb;
            float rl = 1.0f / lfin;
            size_t obase = (size_t)(b * SEQ + qt * 64 + r) * DKV;
            #pragma unroll
            for (int n = 0; n < 8; ++n)
                out[obase + n * 16 + lrow] =
                    (o[n][j] * ca + obuf[r * 128 + n * 16 + lrow] * cb) * rl;
        }
    }
}

extern "C" void kernel_launch(void* const* d_in, const int* in_sizes, int n_in,
                              void* d_out, int out_size, void* d_ws, size_t ws_size,
                              hipStream_t stream) {
    const float* X  = (const float*)d_in[0];
    const float* Wq = (const float*)d_in[1];
    const float* bq = (const float*)d_in[2];
    const float* Wk = (const float*)d_in[3];
    const float* bk = (const float*)d_in[4];
    const float* Wv = (const float*)d_in[5];
    const float* bv = (const float*)d_in[6];
    float* out = (float*)d_out;

    const size_t nqe = (size_t)NB * SEQ * DKV;            // 2M elements
    _Float16* Qh  = (_Float16*)d_ws;
    _Float16* Kh  = Qh  + nqe;
    _Float16* VTh = Kh  + nqe;
    _Float16* WTh = VTh + nqe;                            // 3*128*1024 f16

    prep_wt<<<(3 * 1024 * 128) / 256, 256, 0, stream>>>(Wq, Wk, Wv, WTh);
    qkv_proj<<<(NB * SEQ / 64) * 3, 256, 0, stream>>>(X, bq, bk, bv, WTh, Qh, Kh, VTh);
    attn_kernel<<<NB * 64, 1024, 0, stream>>>(Qh, Kh, VTh, out);
}

// Round 4
// 281.356 us; speedup vs baseline: 1.0192x; 1.0192x over previous
//
#include <hip/hip_runtime.h>

#define NB 4
#define SEQ 4096
#define DIMK 1024
#define DKV 128
#define SCALE 0.08838834764831845f   // 1/sqrt(128)

typedef float  f32x4 __attribute__((ext_vector_type(4)));
typedef _Float16 f16x8 __attribute__((ext_vector_type(8)));

// ---------------- kernel 0: transpose W -> f16 WT[3][128][1024] ----------------
__global__ void prep_wt(const float* __restrict__ Wq, const float* __restrict__ Wk,
                        const float* __restrict__ Wv, _Float16* __restrict__ WT) {
    int tid = blockIdx.x * 256 + threadIdx.x;        // 3*1024*128 = 393216 threads
    int n  = tid & 127;
    int k  = (tid >> 7) & 1023;
    int w3 = tid >> 17;
    const float* W = (w3 == 0) ? Wq : (w3 == 1) ? Wk : Wv;
    WT[((size_t)w3 * 128 + n) * 1024 + k] = (_Float16)W[(size_t)k * 128 + n];
}

// ---------------- kernel 1: QKV projection, w3-split (unchanged, verified) ----------------
__global__ __launch_bounds__(256) void qkv_proj(
    const float* __restrict__ X,
    const float* __restrict__ bq, const float* __restrict__ bk, const float* __restrict__ bv,
    const _Float16* __restrict__ WT,
    _Float16* __restrict__ Qh, _Float16* __restrict__ Kh, _Float16* __restrict__ VTh) {

    __shared__ __attribute__((aligned(16))) _Float16 WTs[128 * 40];
    const int t = threadIdx.x;
    const int w = t >> 6, l = t & 63;
    const int lrow = l & 15, lg = l >> 4;
    const int w3   = blockIdx.x % 3;
    const int tile = blockIdx.x / 3;
    const int r0 = tile * 64;

    f32x4 acc[8] = {};
    const float* xrow = X + (size_t)(r0 + w * 16 + lrow) * DIMK;
    const _Float16* Wbase = WT + (size_t)w3 * 128 * 1024;

    for (int k0 = 0; k0 < DIMK; k0 += 32) {
        __syncthreads();
        #pragma unroll
        for (int i = 0; i < 2; ++i) {
            int c = t + 256 * i;
            int row = c >> 2, part = c & 3;
            *(int4*)((char*)WTs + row * 80 + part * 16) =
                *(const int4*)(Wbase + (size_t)row * 1024 + k0 + part * 8);
        }
        __syncthreads();
        f16x8 a;
        const float* xp = xrow + k0 + lg * 8;
        float4 x0 = *(const float4*)(xp);
        float4 x1 = *(const float4*)(xp + 4);
        a[0] = (_Float16)x0.x; a[1] = (_Float16)x0.y; a[2] = (_Float16)x0.z; a[3] = (_Float16)x0.w;
        a[4] = (_Float16)x1.x; a[5] = (_Float16)x1.y; a[6] = (_Float16)x1.z; a[7] = (_Float16)x1.w;

        #pragma unroll
        for (int n = 0; n < 8; ++n) {
            f16x8 bf = *(const f16x8*)((const char*)WTs + (n * 16 + lrow) * 80 + lg * 16);
            acc[n] = __builtin_amdgcn_mfma_f32_16x16x32_f16(a, bf, acc[n], 0, 0, 0);
        }
    }
    const float* bias = (w3 == 0) ? bq : (w3 == 1) ? bk : bv;
    #pragma unroll
    for (int n = 0; n < 8; ++n) {
        int col = n * 16 + lrow;
        float bv_ = bias[col];
        #pragma unroll
        for (int j = 0; j < 4; ++j) {
            int grow = r0 + w * 16 + lg * 4 + j;
            float val = acc[n][j] + bv_;
            if (w3 == 0) {
                Qh[(size_t)grow * DKV + col] = (_Float16)(val * SCALE);
            } else if (w3 == 1) {
                Kh[(size_t)grow * DKV + col] = (_Float16)val;
            } else {
                int b = grow >> 12, sp = grow & 4095;
                VTh[((size_t)b * DKV + col) * SEQ + sp] = (_Float16)val;
            }
        }
    }
}

// ---------------- kernel 2: flash attention, in-block 4-way KV-split ----------------
// grid 256 (XCD-swizzled), block 1024 thr = 16 waves = 4 groups x 4 waves.
// Group g handles keys [g*1024, (g+1)*1024) for the block's 64 q-rows; LDS tree-merge.
// LDS: Ks 4x16KB + VTs 4x16KB + Ps 16x2KB = 163840 B (exactly 160 KiB).
// NOTE: no min-occupancy hint — (1024,4) forced VGPR=64 and spilled ~730MB to scratch.
__global__ __launch_bounds__(1024) void attn_kernel(
    const _Float16* __restrict__ Qh, const _Float16* __restrict__ Kh,
    const _Float16* __restrict__ VTh, float* __restrict__ out) {

    __shared__ __attribute__((aligned(16))) _Float16 Ks[4][64 * 128];
    __shared__ __attribute__((aligned(16))) _Float16 VTs[4][128 * 64];
    __shared__ __attribute__((aligned(16))) _Float16 Ps[16][16 * 64];

    const int t = threadIdx.x;
    const int w = t >> 6, l = t & 63;
    const int lrow = l & 15, lg = l >> 4;
    const int g  = t >> 8;            // kv group 0..3 (256 contiguous threads)
    const int wq = w & 3;             // q-sub-block within the 64 q-rows
    const int lt = t & 255;           // thread within group (for staging)

    // XCD-chunked swizzle: XCD x gets contiguous works [x*32, x*32+32)
    const int work = (blockIdx.x & 7) * 32 + (blockIdx.x >> 3);
    const int b  = work >> 6;
    const int qt = work & 63;
    const int qrow = b * SEQ + qt * 64 + wq * 16 + lrow;

    f16x8 qfrag[4];
    #pragma unroll
    for (int ds = 0; ds < 4; ++ds)
        qfrag[ds] = *(const f16x8*)(Qh + (size_t)qrow * DKV + ds * 32 + lg * 8);

    f32x4 o[8] = {};
    float mrun[4] = {-INFINITY, -INFINITY, -INFINITY, -INFINITY};
    float lrun[4] = {0.f, 0.f, 0.f, 0.f};

    char* KsG = (char*)&Ks[g][0];
    char* VsG = (char*)&VTs[g][0];
    char* PsW = (char*)&Ps[w][0];

    for (int kt = 0; kt < 16; ++kt) {
        const int k0 = g * 1024 + kt * 64;
        __syncthreads();
        // stage K tile 64x128 f16 (group-private), XOR-swizzled
        #pragma unroll
        for (int i = 0; i < 4; ++i) {
            int c = lt + 256 * i; int row = c >> 4, part = c & 15;
            *(int4*)(KsG + row * 256 + ((part * 16) ^ ((row & 7) << 4))) =
                *(const int4*)(Kh + (size_t)(b * SEQ + k0 + row) * DKV + part * 8);
        }
        // stage V^T tile 128x64 f16 (group-private), swizzled
        #pragma unroll
        for (int i = 0; i < 4; ++i) {
            int c = lt + 256 * i; int dv = c >> 3, part = c & 7;
            *(int4*)(VsG + dv * 128 + ((part * 16) ^ ((dv & 7) << 4))) =
                *(const int4*)(VTh + (size_t)(b * DKV + dv) * SEQ + k0 + part * 8);
        }
        __syncthreads();

        // S = Q K^T (scale folded into Q)
        f32x4 sacc[4] = {};
        __builtin_amdgcn_s_setprio(1);
        #pragma unroll
        for (int n = 0; n < 4; ++n) {
            int rn = n * 16 + lrow;
            #pragma unroll
            for (int ds = 0; ds < 4; ++ds) {
                f16x8 kf = *(const f16x8*)(KsG + rn * 256 +
                                           ((ds * 64 + lg * 16) ^ ((rn & 7) << 4)));
                sacc[n] = __builtin_amdgcn_mfma_f32_16x16x32_f16(qfrag[ds], kf, sacc[n], 0, 0, 0);
            }
        }
        __builtin_amdgcn_s_setprio(0);

        // online softmax with defer-max (T13, THR=8)
        float mt[4], ls[4];
        #pragma unroll
        for (int j = 0; j < 4; ++j)
            mt[j] = fmaxf(fmaxf(sacc[0][j], sacc[1][j]), fmaxf(sacc[2][j], sacc[3][j]));
        #pragma unroll
        for (int off = 1; off <= 8; off <<= 1)
            #pragma unroll
            for (int j = 0; j < 4; ++j)
                mt[j] = fmaxf(mt[j], __shfl_xor(mt[j], off));

        int need = (mt[0] > mrun[0] + 8.f) | (mt[1] > mrun[1] + 8.f) |
                   (mt[2] > mrun[2] + 8.f) | (mt[3] > mrun[3] + 8.f);
        if (__any(need)) {
            #pragma unroll
            for (int j = 0; j < 4; ++j) {
                float mnew = fmaxf(mrun[j], mt[j]);
                float corr = __expf(mrun[j] - mnew);
                mrun[j] = mnew;
                ls[j] = 0.f;
                #pragma unroll
                for (int n = 0; n < 4; ++n) {
                    sacc[n][j] = __expf(sacc[n][j] - mnew);
                    ls[j] += sacc[n][j];
                }
                #pragma unroll
                for (int n = 0; n < 8; ++n) o[n][j] *= corr;
                lrun[j] *= corr;
            }
        } else {
            #pragma unroll
            for (int j = 0; j < 4; ++j) {
                ls[j] = 0.f;
                #pragma unroll
                for (int n = 0; n < 4; ++n) {
                    sacc[n][j] = __expf(sacc[n][j] - mrun[j]);
                    ls[j] += sacc[n][j];
                }
            }
        }
        #pragma unroll
        for (int off = 1; off <= 8; off <<= 1)
            #pragma unroll
            for (int j = 0; j < 4; ++j)
                ls[j] += __shfl_xor(ls[j], off);
        #pragma unroll
        for (int j = 0; j < 4; ++j) lrun[j] += ls[j];

        // P -> wave-private LDS (128B rows, swizzled); no block barrier needed
        #pragma unroll
        for (int n = 0; n < 4; ++n)
            #pragma unroll
            for (int j = 0; j < 4; ++j) {
                int r = lg * 4 + j;
                *((_Float16*)(PsW + r * 128 +
                              (((n * 16 + lrow) * 2) ^ ((r & 7) << 4)))) = (_Float16)sacc[n][j];
            }
        asm volatile("s_waitcnt lgkmcnt(0)" ::: "memory");

        // O += P V
        __builtin_amdgcn_s_setprio(1);
        #pragma unroll
        for (int h = 0; h < 2; ++h) {
            f16x8 pf = *(const f16x8*)(PsW + lrow * 128 +
                                       ((h * 64 + lg * 16) ^ ((lrow & 7) << 4)));
            #pragma unroll
            for (int n = 0; n < 8; ++n) {
                int rv = n * 16 + lrow;
                f16x8 vf = *(const f16x8*)(VsG + rv * 128 +
                                           ((h * 64 + lg * 16) ^ ((rv & 7) << 4)));
                o[n] = __builtin_amdgcn_mfma_f32_16x16x32_f16(pf, vf, o[n], 0, 0, 0);
            }
        }
        __builtin_amdgcn_s_setprio(0);
    }

    // -------- tree-merge of 4 group partials via LDS (reuses Ks/VTs space) --------
    float* obuf  = (float*)&Ks[0][0];    // 2 buffers x 64x128 f32 = 64 KB
    float* mlbuf = (float*)&VTs[0][0];   // 2 x 64 x {m,l}

    __syncthreads();
    // round A: groups 1,3 publish; groups 0,2 merge
    if (g == 1 || g == 3) {
        int sb = (g == 3);
        #pragma unroll
        for (int n = 0; n < 8; ++n)
            #pragma unroll
            for (int j = 0; j < 4; ++j)
                obuf[sb * 8192 + (wq * 16 + lg * 4 + j) * 128 + n * 16 + lrow] = o[n][j];
        if (lrow == 0)
            #pragma unroll
            for (int j = 0; j < 4; ++j) {
                int r = wq * 16 + lg * 4 + j;
                mlbuf[sb * 128 + r * 2 + 0] = mrun[j];
                mlbuf[sb * 128 + r * 2 + 1] = lrun[j];
            }
    }
    __syncthreads();
    if (g == 0 || g == 2) {
        int sb = (g == 2);
        #pragma unroll
        for (int j = 0; j < 4; ++j) {
            int r = wq * 16 + lg * 4 + j;
            float mb = mlbuf[sb * 128 + r * 2 + 0];
            float lb = mlbuf[sb * 128 + r * 2 + 1];
            float mn = fmaxf(mrun[j], mb);
            float ca = __expf(mrun[j] - mn);
            float cb = __expf(mb - mn);
            mrun[j] = mn;
            lrun[j] = lrun[j] * ca + lb * cb;
            #pragma unroll
            for (int n = 0; n < 8; ++n)
                o[n][j] = o[n][j] * ca + obuf[sb * 8192 + r * 128 + n * 16 + lrow] * cb;
        }
    }
    __syncthreads();
    // round B: group 2 publishes merged; group 0 merges and writes out
    if (g == 2) {
        #pragma unroll
        for (int n = 0; n < 8; ++n)
            #pragma unroll
            for (int j = 0; j < 4; ++j)
                obuf[(wq * 16 + lg * 4 + j) * 128 + n * 16 + lrow] = o[n][j];
        if (lrow == 0)
            #pragma unroll
            for (int j = 0; j < 4; ++j) {
                int r = wq * 16 + lg * 4 + j;
                mlbuf[r * 2 + 0] = mrun[j];
                mlbuf[r * 2 + 1] = lrun[j];
            }
    }
    __syncthreads();
    if (g == 0) {
        #pragma unroll
        for (int j = 0; j < 4; ++j) {
            int r = wq * 16 + lg * 4 + j;
            float mb = mlbuf[r * 2 + 0];
            float lb = mlbuf[r * 2 + 1];
            float mn = fmaxf(mrun[j], mb);
            float ca = __expf(mrun[j] - mn);
            float cb = __expf(mb - mn);
            float lfin = lrun[j] * ca + lb * cb;
            float rl = 1.0f / lfin;
            size_t obase = (size_t)(b * SEQ + qt * 64 + r) * DKV;
            #pragma unroll
            for (int n = 0; n < 8; ++n)
                out[obase + n * 16 + lrow] =
                    (o[n][j] * ca + obuf[r * 128 + n * 16 + lrow] * cb) * rl;
        }
    }
}

extern "C" void kernel_launch(void* const* d_in, const int* in_sizes, int n_in,
                              void* d_out, int out_size, void* d_ws, size_t ws_size,
                              hipStream_t stream) {
    const float* X  = (const float*)d_in[0];
    const float* Wq = (const float*)d_in[1];
    const float* bq = (const float*)d_in[2];
    const float* Wk = (const float*)d_in[3];
    const float* bk = (const float*)d_in[4];
    const float* Wv = (const float*)d_in[5];
    const float* bv = (const float*)d_in[6];
    float* out = (float*)d_out;

    const size_t nqe = (size_t)NB * SEQ * DKV;            // 2M elements
    _Float16* Qh  = (_Float16*)d_ws;
    _Float16* Kh  = Qh  + nqe;
    _Float16* VTh = Kh  + nqe;
    _Float16* WTh = VTh + nqe;                            // 3*128*1024 f16

    prep_wt<<<(3 * 1024 * 128) / 256, 256, 0, stream>>>(Wq, Wk, Wv, WTh);
    qkv_proj<<<(NB * SEQ / 64) * 3, 256, 0, stream>>>(X, bq, bk, bv, WTh, Qh, Kh, VTh);
    attn_kernel<<<NB * 64, 1024, 0, stream>>>(Qh, Kh, VTh, out);
}

// Round 5
// 214.728 us; speedup vs baseline: 1.3355x; 1.3103x over previous
//
#include <hip/hip_runtime.h>

#define NB 4
#define SEQ 4096
#define DIMK 1024
#define DKV 128
#define NS (NB * SEQ)
#define SCALE 0.08838834764831845f   // 1/sqrt(128)

typedef float  f32x4 __attribute__((ext_vector_type(4)));
typedef _Float16 f16x8 __attribute__((ext_vector_type(8)));
typedef _Float16 f16x4 __attribute__((ext_vector_type(4)));

// ---------------- kernel 0: transpose W -> f16 WT[3][128][1024] ----------------
__global__ void prep_wt(const float* __restrict__ Wq, const float* __restrict__ Wk,
                        const float* __restrict__ Wv, _Float16* __restrict__ WT) {
    int tid = blockIdx.x * 256 + threadIdx.x;
    int n  = tid & 127;
    int k  = (tid >> 7) & 1023;
    int w3 = tid >> 17;
    const float* W = (w3 == 0) ? Wq : (w3 == 1) ? Wk : Wv;
    WT[((size_t)w3 * 128 + n) * 1024 + k] = (_Float16)W[(size_t)k * 128 + n];
}

// ---------------- kernel 1: QKV projection, w3-split + X prefetch ----------------
__global__ __launch_bounds__(256) void qkv_proj(
    const float* __restrict__ X,
    const float* __restrict__ bq, const float* __restrict__ bk, const float* __restrict__ bv,
    const _Float16* __restrict__ WT,
    _Float16* __restrict__ Qh, _Float16* __restrict__ Kh, _Float16* __restrict__ VTh) {

    __shared__ __attribute__((aligned(16))) _Float16 WTs[128 * 40];
    const int t = threadIdx.x;
    const int w = t >> 6, l = t & 63;
    const int lrow = l & 15, lg = l >> 4;
    const int w3   = blockIdx.x % 3;
    const int tile = blockIdx.x / 3;
    const int r0 = tile * 64;

    f32x4 acc[8] = {};
    const float* xrow = X + (size_t)(r0 + w * 16 + lrow) * DIMK;
    const _Float16* Wbase = WT + (size_t)w3 * 128 * 1024;

    // prefetch first X fragment
    float4 xc0 = *(const float4*)(xrow + lg * 8);
    float4 xc1 = *(const float4*)(xrow + lg * 8 + 4);

    for (int k0 = 0; k0 < DIMK; k0 += 32) {
        __syncthreads();
        #pragma unroll
        for (int i = 0; i < 2; ++i) {
            int c = t + 256 * i;
            int row = c >> 2, part = c & 3;
            *(int4*)((char*)WTs + row * 80 + part * 16) =
                *(const int4*)(Wbase + (size_t)row * 1024 + k0 + part * 8);
        }
        // issue next X loads before the barrier (hide latency under MFMA)
        float4 xn0, xn1;
        if (k0 + 32 < DIMK) {
            xn0 = *(const float4*)(xrow + k0 + 32 + lg * 8);
            xn1 = *(const float4*)(xrow + k0 + 32 + lg * 8 + 4);
        }
        __syncthreads();
        f16x8 a;
        a[0] = (_Float16)xc0.x; a[1] = (_Float16)xc0.y; a[2] = (_Float16)xc0.z; a[3] = (_Float16)xc0.w;
        a[4] = (_Float16)xc1.x; a[5] = (_Float16)xc1.y; a[6] = (_Float16)xc1.z; a[7] = (_Float16)xc1.w;

        __builtin_amdgcn_s_setprio(1);
        #pragma unroll
        for (int n = 0; n < 8; ++n) {
            f16x8 bf = *(const f16x8*)((const char*)WTs + (n * 16 + lrow) * 80 + lg * 16);
            acc[n] = __builtin_amdgcn_mfma_f32_16x16x32_f16(a, bf, acc[n], 0, 0, 0);
        }
        __builtin_amdgcn_s_setprio(0);
        xc0 = xn0; xc1 = xn1;
    }
    const float* bias = (w3 == 0) ? bq : (w3 == 1) ? bk : bv;
    #pragma unroll
    for (int n = 0; n < 8; ++n) {
        int col = n * 16 + lrow;
        float bv_ = bias[col];
        #pragma unroll
        for (int j = 0; j < 4; ++j) {
            int grow = r0 + w * 16 + lg * 4 + j;
            float val = acc[n][j] + bv_;
            if (w3 == 0) {
                Qh[(size_t)grow * DKV + col] = (_Float16)(val * SCALE);
            } else if (w3 == 1) {
                Kh[(size_t)grow * DKV + col] = (_Float16)val;
            } else {
                int b = grow >> 12, sp = grow & 4095;
                VTh[((size_t)b * DKV + col) * SEQ + sp] = (_Float16)val;
            }
        }
    }
}

// ---------------- kernel 2: flash attention, global KV-split + dbuf LDS ----------------
// block 256 thr (4 waves), 64 q-rows, keys [s*kps, (s+1)*kps).
// LDS: Ks 2x16KB + VTs 2x16KB + Ps 4x2KB = 72KB -> 2 blocks/CU.
// T14 schedule: load(kt+1)->regs ; barrier ; compute(kt) ; write regs->other buf.
__global__ __launch_bounds__(256) void attn_kernel(
    const _Float16* __restrict__ Qh, const _Float16* __restrict__ Kh,
    const _Float16* __restrict__ VTh, float* __restrict__ out,
    _Float16* __restrict__ O1h, float* __restrict__ ml,
    int nsplit, int kps) {

    __shared__ __attribute__((aligned(16))) _Float16 Ks[2][64 * 128];
    __shared__ __attribute__((aligned(16))) _Float16 VTs[2][128 * 64];
    __shared__ __attribute__((aligned(16))) _Float16 Ps[4][16 * 64];

    const int t = threadIdx.x;
    const int w = t >> 6, l = t & 63;
    const int lrow = l & 15, lg = l >> 4;

    // XCD-chunked swizzle (grid is a multiple of 8)
    const int nwork = NB * nsplit * 64;
    const int cpx = nwork >> 3;
    const int work = (blockIdx.x & 7) * cpx + (blockIdx.x >> 3);
    const int b   = work / (nsplit * 64);
    const int rem = work % (nsplit * 64);
    const int s   = rem / 64;
    const int qt  = rem % 64;
    const int qrow = b * SEQ + qt * 64 + w * 16 + lrow;

    f16x8 qfrag[4];
    #pragma unroll
    for (int ds = 0; ds < 4; ++ds)
        qfrag[ds] = *(const f16x8*)(Qh + (size_t)qrow * DKV + ds * 32 + lg * 8);

    f32x4 o[8] = {};
    float mrun[4] = {-INFINITY, -INFINITY, -INFINITY, -INFINITY};
    float lrun[4] = {0.f, 0.f, 0.f, 0.f};

    char* PsW = (char*)&Ps[w][0];
    const int kbase = s * kps;
    const int kts = kps >> 6;

    int4 kreg[4], vreg[4];

    // ---- staging helpers (manually unrolled via macros on constant i) ----
#define LOADK(i) { int c = t + 256 * (i); int row = c >> 4, part = c & 15;                 \
        kreg[i] = *(const int4*)(Kh + (size_t)(b * SEQ + k0 + row) * DKV + part * 8); }
#define LOADV(i) { int c = t + 256 * (i); int dv = c >> 3, part = c & 7;                   \
        vreg[i] = *(const int4*)(VTh + (size_t)(b * DKV + dv) * SEQ + k0 + part * 8); }
#define WRITEK(i, buf) { int c = t + 256 * (i); int row = c >> 4, part = c & 15;           \
        *(int4*)((char*)&Ks[buf][0] + row * 256 + ((part * 16) ^ ((row & 7) << 4))) = kreg[i]; }
#define WRITEV(i, buf) { int c = t + 256 * (i); int dv = c >> 3, part = c & 7;             \
        *(int4*)((char*)&VTs[buf][0] + dv * 128 + ((part * 16) ^ ((dv & 7) << 4))) = vreg[i]; }

    // prologue: tile 0 -> buf 0
    {
        const int k0 = kbase;
        LOADK(0) LOADK(1) LOADK(2) LOADK(3)
        LOADV(0) LOADV(1) LOADV(2) LOADV(3)
        WRITEK(0, 0) WRITEK(1, 0) WRITEK(2, 0) WRITEK(3, 0)
        WRITEV(0, 0) WRITEV(1, 0) WRITEV(2, 0) WRITEV(3, 0)
    }

    for (int kt = 0; kt < kts; ++kt) {
        const int cur = kt & 1;
        // issue next-tile global loads early (hide under this tile's compute)
        if (kt + 1 < kts) {
            const int k0 = kbase + (kt + 1) * 64;
            LOADK(0) LOADK(1) LOADK(2) LOADK(3)
            LOADV(0) LOADV(1) LOADV(2) LOADV(3)
        }
        __syncthreads();   // buf[cur] writes visible; all waves done reading buf[cur^1]

        char* KsG = (char*)&Ks[cur][0];
        char* VsG = (char*)&VTs[cur][0];

        // S = Q K^T (scale folded into Q)
        f32x4 sacc[4] = {};
        __builtin_amdgcn_s_setprio(1);
        #pragma unroll
        for (int n = 0; n < 4; ++n) {
            int rn = n * 16 + lrow;
            #pragma unroll
            for (int ds = 0; ds < 4; ++ds) {
                f16x8 kf = *(const f16x8*)(KsG + rn * 256 +
                                           ((ds * 64 + lg * 16) ^ ((rn & 7) << 4)));
                sacc[n] = __builtin_amdgcn_mfma_f32_16x16x32_f16(qfrag[ds], kf, sacc[n], 0, 0, 0);
            }
        }
        __builtin_amdgcn_s_setprio(0);

        // online softmax with defer-max (T13, THR=8)
        float mt[4], ls[4];
        #pragma unroll
        for (int j = 0; j < 4; ++j)
            mt[j] = fmaxf(fmaxf(sacc[0][j], sacc[1][j]), fmaxf(sacc[2][j], sacc[3][j]));
        #pragma unroll
        for (int off = 1; off <= 8; off <<= 1)
            #pragma unroll
            for (int j = 0; j < 4; ++j)
                mt[j] = fmaxf(mt[j], __shfl_xor(mt[j], off));

        int need = (mt[0] > mrun[0] + 8.f) | (mt[1] > mrun[1] + 8.f) |
                   (mt[2] > mrun[2] + 8.f) | (mt[3] > mrun[3] + 8.f);
        if (__any(need)) {
            #pragma unroll
            for (int j = 0; j < 4; ++j) {
                float mnew = fmaxf(mrun[j], mt[j]);
                float corr = __expf(mrun[j] - mnew);
                mrun[j] = mnew;
                ls[j] = 0.f;
                #pragma unroll
                for (int n = 0; n < 4; ++n) {
                    sacc[n][j] = __expf(sacc[n][j] - mnew);
                    ls[j] += sacc[n][j];
                }
                #pragma unroll
                for (int n = 0; n < 8; ++n) o[n][j] *= corr;
                lrun[j] *= corr;
            }
        } else {
            #pragma unroll
            for (int j = 0; j < 4; ++j) {
                ls[j] = 0.f;
                #pragma unroll
                for (int n = 0; n < 4; ++n) {
                    sacc[n][j] = __expf(sacc[n][j] - mrun[j]);
                    ls[j] += sacc[n][j];
                }
            }
        }
        #pragma unroll
        for (int off = 1; off <= 8; off <<= 1)
            #pragma unroll
            for (int j = 0; j < 4; ++j)
                ls[j] += __shfl_xor(ls[j], off);
        #pragma unroll
        for (int j = 0; j < 4; ++j) lrun[j] += ls[j];

        // P -> wave-private LDS (swizzled); per-wave ordering via lgkmcnt
        #pragma unroll
        for (int n = 0; n < 4; ++n)
            #pragma unroll
            for (int j = 0; j < 4; ++j) {
                int r = lg * 4 + j;
                *((_Float16*)(PsW + r * 128 +
                              (((n * 16 + lrow) * 2) ^ ((r & 7) << 4)))) = (_Float16)sacc[n][j];
            }
        asm volatile("s_waitcnt lgkmcnt(0)" ::: "memory");

        // O += P V
        __builtin_amdgcn_s_setprio(1);
        #pragma unroll
        for (int h = 0; h < 2; ++h) {
            f16x8 pf = *(const f16x8*)(PsW + lrow * 128 +
                                       ((h * 64 + lg * 16) ^ ((lrow & 7) << 4)));
            #pragma unroll
            for (int n = 0; n < 8; ++n) {
                int rv = n * 16 + lrow;
                f16x8 vf = *(const f16x8*)(VsG + rv * 128 +
                                           ((h * 64 + lg * 16) ^ ((rv & 7) << 4)));
                o[n] = __builtin_amdgcn_mfma_f32_16x16x32_f16(pf, vf, o[n], 0, 0, 0);
            }
        }
        __builtin_amdgcn_s_setprio(0);

        // write next tile into the other buffer (safe: everyone passed this tile's barrier)
        if (kt + 1 < kts) {
            const int nb_ = cur ^ 1;
            WRITEK(0, nb_) WRITEK(1, nb_) WRITEK(2, nb_) WRITEK(3, nb_)
            WRITEV(0, nb_) WRITEV(1, nb_) WRITEV(2, nb_) WRITEV(3, nb_)
        }
    }

    // ---- epilogue: normalized output per split ----
    float rl[4];
    #pragma unroll
    for (int j = 0; j < 4; ++j) rl[j] = 1.0f / lrun[j];

    if (nsplit == 1) {
        const size_t obase = (size_t)(b * SEQ + qt * 64 + w * 16) * DKV;
        #pragma unroll
        for (int n = 0; n < 8; ++n)
            #pragma unroll
            for (int j = 0; j < 4; ++j)
                out[obase + (size_t)(lg * 4 + j) * DKV + n * 16 + lrow] = o[n][j] * rl[j];
    } else {
        #pragma unroll
        for (int j = 0; j < 4; ++j) {
            int qg = b * SEQ + qt * 64 + w * 16 + lg * 4 + j;
            if (s == 0) {
                #pragma unroll
                for (int n = 0; n < 8; ++n)
                    out[(size_t)qg * DKV + n * 16 + lrow] = o[n][j] * rl[j];
            } else {
                #pragma unroll
                for (int n = 0; n < 8; ++n)
                    O1h[(size_t)qg * DKV + n * 16 + lrow] = (_Float16)(o[n][j] * rl[j]);
            }
            if (lrow == 0) {
                ml[(size_t)(s * 2 + 0) * NS + qg] = mrun[j];
                ml[(size_t)(s * 2 + 1) * NS + qg] = lrun[j];
            }
        }
    }
}

// ---------------- kernel 3: combine two split partials ----------------
__global__ __launch_bounds__(256) void combine_kernel(
    float* __restrict__ out, const _Float16* __restrict__ O1h,
    const float* __restrict__ ml) {
    int g = blockIdx.x * 256 + threadIdx.x;   // NS*32 threads, 4 cols each
    int r = g >> 5;
    int c0 = (g & 31) * 4;
    float m0 = ml[r],          l0 = ml[(size_t)NS + r];
    float m1 = ml[(size_t)2 * NS + r], l1 = ml[(size_t)3 * NS + r];
    float M = fmaxf(m0, m1);
    float w0 = l0 * __expf(m0 - M);
    float w1 = l1 * __expf(m1 - M);
    float inv = 1.0f / (w0 + w1);
    float4 a = *(const float4*)(out + (size_t)r * DKV + c0);
    f16x4 h = *(const f16x4*)(O1h + (size_t)r * DKV + c0);
    float4 res;
    res.x = (w0 * a.x + w1 * (float)h[0]) * inv;
    res.y = (w0 * a.y + w1 * (float)h[1]) * inv;
    res.z = (w0 * a.z + w1 * (float)h[2]) * inv;
    res.w = (w0 * a.w + w1 * (float)h[3]) * inv;
    *(float4*)(out + (size_t)r * DKV + c0) = res;
}

extern "C" void kernel_launch(void* const* d_in, const int* in_sizes, int n_in,
                              void* d_out, int out_size, void* d_ws, size_t ws_size,
                              hipStream_t stream) {
    const float* X  = (const float*)d_in[0];
    const float* Wq = (const float*)d_in[1];
    const float* bq = (const float*)d_in[2];
    const float* Wk = (const float*)d_in[3];
    const float* bk = (const float*)d_in[4];
    const float* Wv = (const float*)d_in[5];
    const float* bv = (const float*)d_in[6];
    float* out = (float*)d_out;

    const size_t nqe = (size_t)NB * SEQ * DKV;            // 2M elements
    _Float16* Qh  = (_Float16*)d_ws;
    _Float16* Kh  = Qh  + nqe;
    _Float16* VTh = Kh  + nqe;
    _Float16* WTh = VTh + nqe;                            // 3*128*1024 f16
    size_t f16_bytes = (3 * nqe + (size_t)3 * 128 * 1024) * sizeof(_Float16);
    f16_bytes = (f16_bytes + 255) & ~(size_t)255;

    // split-1 partial (f16, normalized) + m/l stats (f32 x4)
    size_t o1_bytes = nqe * sizeof(_Float16);
    size_t ml_bytes = (size_t)4 * NS * sizeof(float);
    size_t need2 = f16_bytes + o1_bytes + ml_bytes;
    int nsplit = (ws_size >= need2) ? 2 : 1;
    int kps = SEQ / nsplit;

    _Float16* O1h = (_Float16*)((char*)d_ws + f16_bytes);
    float* ml = (float*)((char*)d_ws + f16_bytes + o1_bytes);

    prep_wt<<<(3 * 1024 * 128) / 256, 256, 0, stream>>>(Wq, Wk, Wv, WTh);
    qkv_proj<<<(NB * SEQ / 64) * 3, 256, 0, stream>>>(X, bq, bk, bv, WTh, Qh, Kh, VTh);
    attn_kernel<<<NB * nsplit * 64, 256, 0, stream>>>(Qh, Kh, VTh, out, O1h, ml,
                                                      nsplit, kps);
    if (nsplit == 2)
        combine_kernel<<<(NS * 32) / 256, 256, 0, stream>>>(out, O1h, ml);
}

// Round 6
// 148.546 us; speedup vs baseline: 1.9305x; 1.4455x over previous
//
#include <hip/hip_runtime.h>

#define NB 4
#define SEQ 4096
#define DIMK 1024
#define DKV 128
#define SCALE 0.08838834764831845f   // 1/sqrt(128)

typedef float  f32x4 __attribute__((ext_vector_type(4)));
typedef _Float16 f16x8 __attribute__((ext_vector_type(8)));

// ---------------- kernel 0: transpose W -> f16 WT[3][128][1024] ----------------
__global__ void prep_wt(const float* __restrict__ Wq, const float* __restrict__ Wk,
                        const float* __restrict__ Wv, _Float16* __restrict__ WT) {
    int tid = blockIdx.x * 256 + threadIdx.x;
    int n  = tid & 127;
    int k  = (tid >> 7) & 1023;
    int w3 = tid >> 17;
    const float* W = (w3 == 0) ? Wq : (w3 == 1) ? Wk : Wv;
    WT[((size_t)w3 * 128 + n) * 1024 + k] = (_Float16)W[(size_t)k * 128 + n];
}

// ---------------- kernel 1: QKV projection, w3-split + X prefetch ----------------
__global__ __launch_bounds__(256) void qkv_proj(
    const float* __restrict__ X,
    const float* __restrict__ bq, const float* __restrict__ bk, const float* __restrict__ bv,
    const _Float16* __restrict__ WT,
    _Float16* __restrict__ Qh, _Float16* __restrict__ Kh, _Float16* __restrict__ VTh) {

    __shared__ __attribute__((aligned(16))) _Float16 WTs[128 * 40];
    const int t = threadIdx.x;
    const int w = t >> 6, l = t & 63;
    const int lrow = l & 15, lg = l >> 4;
    const int w3   = blockIdx.x % 3;
    const int tile = blockIdx.x / 3;
    const int r0 = tile * 64;

    f32x4 acc[8] = {};
    const float* xrow = X + (size_t)(r0 + w * 16 + lrow) * DIMK;
    const _Float16* Wbase = WT + (size_t)w3 * 128 * 1024;

    float4 xc0 = *(const float4*)(xrow + lg * 8);
    float4 xc1 = *(const float4*)(xrow + lg * 8 + 4);

    for (int k0 = 0; k0 < DIMK; k0 += 32) {
        __syncthreads();
        #pragma unroll
        for (int i = 0; i < 2; ++i) {
            int c = t + 256 * i;
            int row = c >> 2, part = c & 3;
            *(int4*)((char*)WTs + row * 80 + part * 16) =
                *(const int4*)(Wbase + (size_t)row * 1024 + k0 + part * 8);
        }
        float4 xn0, xn1;
        if (k0 + 32 < DIMK) {
            xn0 = *(const float4*)(xrow + k0 + 32 + lg * 8);
            xn1 = *(const float4*)(xrow + k0 + 32 + lg * 8 + 4);
        }
        __syncthreads();
        f16x8 a;
        a[0] = (_Float16)xc0.x; a[1] = (_Float16)xc0.y; a[2] = (_Float16)xc0.z; a[3] = (_Float16)xc0.w;
        a[4] = (_Float16)xc1.x; a[5] = (_Float16)xc1.y; a[6] = (_Float16)xc1.z; a[7] = (_Float16)xc1.w;

        #pragma unroll
        for (int n = 0; n < 8; ++n) {
            f16x8 bf = *(const f16x8*)((const char*)WTs + (n * 16 + lrow) * 80 + lg * 16);
            acc[n] = __builtin_amdgcn_mfma_f32_16x16x32_f16(a, bf, acc[n], 0, 0, 0);
        }
        xc0 = xn0; xc1 = xn1;
    }
    const float* bias = (w3 == 0) ? bq : (w3 == 1) ? bk : bv;
    #pragma unroll
    for (int n = 0; n < 8; ++n) {
        int col = n * 16 + lrow;
        float bv_ = bias[col];
        #pragma unroll
        for (int j = 0; j < 4; ++j) {
            int grow = r0 + w * 16 + lg * 4 + j;
            float val = acc[n][j] + bv_;
            if (w3 == 0) {
                Qh[(size_t)grow * DKV + col] = (_Float16)(val * SCALE);
            } else if (w3 == 1) {
                Kh[(size_t)grow * DKV + col] = (_Float16)val;
            } else {
                int b = grow >> 12, sp = grow & 4095;
                VTh[((size_t)b * DKV + col) * SEQ + sp] = (_Float16)val;
            }
        }
    }
}

// ---------------- kernel 2: flash attention, in-block 2-way KV-split ----------------
// grid 256 (XCD-swizzled), block 512 thr = 8 waves = 2 groups x 4 waves.
// Group g handles keys [g*2048, (g+1)*2048) for the block's 64 q-rows; one LDS merge.
// LDS: Ks 2x16KB + VTs 2x16KB + Ps 8x2KB = 81920 B.
// 512-thr block => compiler fits 2 waves/SIMD => 256-VGPR cap: ~116 used, NO spill
// (round 3/4's 1024-thr block forced a 128-reg cap -> 730MB scratch; that was the bug).
__global__ __launch_bounds__(512) void attn_kernel(
    const _Float16* __restrict__ Qh, const _Float16* __restrict__ Kh,
    const _Float16* __restrict__ VTh, float* __restrict__ out) {

    __shared__ __attribute__((aligned(16))) _Float16 Ks[2][64 * 128];
    __shared__ __attribute__((aligned(16))) _Float16 VTs[2][128 * 64];
    __shared__ __attribute__((aligned(16))) _Float16 Ps[8][16 * 64];

    const int t = threadIdx.x;
    const int w = t >> 6, l = t & 63;
    const int lrow = l & 15, lg = l >> 4;
    const int g  = t >> 8;            // kv group 0..1
    const int wq = w & 3;             // q-sub-block (16 rows) within the 64 q-rows
    const int lt = t & 255;           // thread within group (for staging)

    // XCD-chunked swizzle over 256 blocks
    const int work = (blockIdx.x & 7) * 32 + (blockIdx.x >> 3);
    const int b  = work >> 6;
    const int qt = work & 63;
    const int qrow = b * SEQ + qt * 64 + wq * 16 + lrow;

    f16x8 qfrag[4];
    #pragma unroll
    for (int ds = 0; ds < 4; ++ds)
        qfrag[ds] = *(const f16x8*)(Qh + (size_t)qrow * DKV + ds * 32 + lg * 8);

    f32x4 o[8] = {};
    float mrun[4] = {-INFINITY, -INFINITY, -INFINITY, -INFINITY};
    float lrun[4] = {0.f, 0.f, 0.f, 0.f};

    char* KsG = (char*)&Ks[g][0];
    char* VsG = (char*)&VTs[g][0];
    char* PsW = (char*)&Ps[w][0];

    for (int kt = 0; kt < 32; ++kt) {
        const int k0 = g * 2048 + kt * 64;
        __syncthreads();
        // stage K tile 64x128 f16 (group-private), XOR-swizzled
        #pragma unroll
        for (int i = 0; i < 4; ++i) {
            int c = lt + 256 * i; int row = c >> 4, part = c & 15;
            *(int4*)(KsG + row * 256 + ((part * 16) ^ ((row & 7) << 4))) =
                *(const int4*)(Kh + (size_t)(b * SEQ + k0 + row) * DKV + part * 8);
        }
        // stage V^T tile 128x64 f16 (group-private), swizzled
        #pragma unroll
        for (int i = 0; i < 4; ++i) {
            int c = lt + 256 * i; int dv = c >> 3, part = c & 7;
            *(int4*)(VsG + dv * 128 + ((part * 16) ^ ((dv & 7) << 4))) =
                *(const int4*)(VTh + (size_t)(b * DKV + dv) * SEQ + k0 + part * 8);
        }
        __syncthreads();

        // S = Q K^T (scale folded into Q)
        f32x4 sacc[4] = {};
        #pragma unroll
        for (int n = 0; n < 4; ++n) {
            int rn = n * 16 + lrow;
            #pragma unroll
            for (int ds = 0; ds < 4; ++ds) {
                f16x8 kf = *(const f16x8*)(KsG + rn * 256 +
                                           ((ds * 64 + lg * 16) ^ ((rn & 7) << 4)));
                sacc[n] = __builtin_amdgcn_mfma_f32_16x16x32_f16(qfrag[ds], kf, sacc[n], 0, 0, 0);
            }
        }

        // online softmax with defer-max (T13, THR=8)
        float mt[4], ls[4];
        #pragma unroll
        for (int j = 0; j < 4; ++j)
            mt[j] = fmaxf(fmaxf(sacc[0][j], sacc[1][j]), fmaxf(sacc[2][j], sacc[3][j]));
        #pragma unroll
        for (int off = 1; off <= 8; off <<= 1)
            #pragma unroll
            for (int j = 0; j < 4; ++j)
                mt[j] = fmaxf(mt[j], __shfl_xor(mt[j], off));

        int need = (mt[0] > mrun[0] + 8.f) | (mt[1] > mrun[1] + 8.f) |
                   (mt[2] > mrun[2] + 8.f) | (mt[3] > mrun[3] + 8.f);
        if (__any(need)) {
            #pragma unroll
            for (int j = 0; j < 4; ++j) {
                float mnew = fmaxf(mrun[j], mt[j]);
                float corr = __expf(mrun[j] - mnew);
                mrun[j] = mnew;
                ls[j] = 0.f;
                #pragma unroll
                for (int n = 0; n < 4; ++n) {
                    sacc[n][j] = __expf(sacc[n][j] - mnew);
                    ls[j] += sacc[n][j];
                }
                #pragma unroll
                for (int n = 0; n < 8; ++n) o[n][j] *= corr;
                lrun[j] *= corr;
            }
        } else {
            #pragma unroll
            for (int j = 0; j < 4; ++j) {
                ls[j] = 0.f;
                #pragma unroll
                for (int n = 0; n < 4; ++n) {
                    sacc[n][j] = __expf(sacc[n][j] - mrun[j]);
                    ls[j] += sacc[n][j];
                }
            }
        }
        #pragma unroll
        for (int off = 1; off <= 8; off <<= 1)
            #pragma unroll
            for (int j = 0; j < 4; ++j)
                ls[j] += __shfl_xor(ls[j], off);
        #pragma unroll
        for (int j = 0; j < 4; ++j) lrun[j] += ls[j];

        // P -> wave-private LDS (swizzled); per-wave ordering via lgkmcnt
        #pragma unroll
        for (int n = 0; n < 4; ++n)
            #pragma unroll
            for (int j = 0; j < 4; ++j) {
                int r = lg * 4 + j;
                *((_Float16*)(PsW + r * 128 +
                              (((n * 16 + lrow) * 2) ^ ((r & 7) << 4)))) = (_Float16)sacc[n][j];
            }
        asm volatile("s_waitcnt lgkmcnt(0)" ::: "memory");

        // O += P V
        #pragma unroll
        for (int h = 0; h < 2; ++h) {
            f16x8 pf = *(const f16x8*)(PsW + lrow * 128 +
                                       ((h * 64 + lg * 16) ^ ((lrow & 7) << 4)));
            #pragma unroll
            for (int n = 0; n < 8; ++n) {
                int rv = n * 16 + lrow;
                f16x8 vf = *(const f16x8*)(VsG + rv * 128 +
                                           ((h * 64 + lg * 16) ^ ((rv & 7) << 4)));
                o[n] = __builtin_amdgcn_mfma_f32_16x16x32_f16(pf, vf, o[n], 0, 0, 0);
            }
        }
    }

    // -------- single-round merge of 2 group partials via LDS (reuses Ks/VTs) --------
    float* obuf  = (float*)&Ks[0][0];    // 64 x 128 f32 = 32 KB (spans Ks[0..1])
    float* mlbuf = (float*)&VTs[0][0];   // 64 x {m,l} f32

    __syncthreads();
    if (g == 1) {
        #pragma unroll
        for (int n = 0; n < 8; ++n)
            #pragma unroll
            for (int j = 0; j < 4; ++j)
                obuf[(wq * 16 + lg * 4 + j) * 128 + n * 16 + lrow] = o[n][j];
        if (lrow == 0)
            #pragma unroll
            for (int j = 0; j < 4; ++j) {
                int r = wq * 16 + lg * 4 + j;
                mlbuf[r * 2 + 0] = mrun[j];
                mlbuf[r * 2 + 1] = lrun[j];
            }
    }
    __syncthreads();
    if (g == 0) {
        #pragma unroll
        for (int j = 0; j < 4; ++j) {
            int r = wq * 16 + lg * 4 + j;
            float mb = mlbuf[r * 2 + 0];
            float lb = mlbuf[r * 2 + 1];
            float mn = fmaxf(mrun[j], mb);
            float ca = __expf(mrun[j] - mn);
            float cb = __expf(mb - mn);
            float lfin = lrun[j] * ca + lb * cb;
            float rl = 1.0f / lfin;
            size_t obase = (size_t)(b * SEQ + qt * 64 + r) * DKV;
            #pragma unroll
            for (int n = 0; n < 8; ++n)
                out[obase + n * 16 + lrow] =
                    (o[n][j] * ca + obuf[r * 128 + n * 16 + lrow] * cb) * rl;
        }
    }
}

extern "C" void kernel_launch(void* const* d_in, const int* in_sizes, int n_in,
                              void* d_out, int out_size, void* d_ws, size_t ws_size,
                              hipStream_t stream) {
    const float* X  = (const float*)d_in[0];
    const float* Wq = (const float*)d_in[1];
    const float* bq = (const float*)d_in[2];
    const float* Wk = (const float*)d_in[3];
    const float* bk = (const float*)d_in[4];
    const float* Wv = (const float*)d_in[5];
    const float* bv = (const float*)d_in[6];
    float* out = (float*)d_out;

    const size_t nqe = (size_t)NB * SEQ * DKV;            // 2M elements
    _Float16* Qh  = (_Float16*)d_ws;
    _Float16* Kh  = Qh  + nqe;
    _Float16* VTh = Kh  + nqe;
    _Float16* WTh = VTh + nqe;                            // 3*128*1024 f16

    prep_wt<<<(3 * 1024 * 128) / 256, 256, 0, stream>>>(Wq, Wk, Wv, WTh);
    qkv_proj<<<(NB * SEQ / 64) * 3, 256, 0, stream>>>(X, bq, bk, bv, WTh, Qh, Kh, VTh);
    attn_kernel<<<NB * 64, 512, 0, stream>>>(Qh, Kh, VTh, out);
}